// Round 6
// baseline (167.735 us; speedup 1.0000x reference)
//
#include <hip/hip_runtime.h>
#include <math.h>

#define T_STEPS 200
#define BB 512
#define DD 32
#define LMBD 1.0f
#define NCH 16         // t-chunks per b (one wave each; h<8 -> 13 t's, else 12)

// ws layout (floats)
#define WS_MINV 0                  // sigma^{-T} [i][k], 1024
#define WS_A    1024               // A = sigma sigma^T, 1024
#define WS_W    2048               // weight[512]
#define WS_PART 2560               // per-b partials [512]
#define WS_DT   3072               // dt[200]
#define WS_SDT  3328               // sqrt(LMBD*dt)[200]
#define WS_V    4096               // v[200][512][32] = 3,276,800
#define WS_CT   3280896            // chunk c-totals [512][16][32]
#define WS_Y    3543040            // chunk Y [512][16][32]
#define WS_M    3805184            // chunk <A,M> scalars [512][16]

// ---------------------------------------------------------------------------
// Kernel 1: prep. weight = exp(lpd+lps+ltw); A = sigma sigma^T; dt/sdt tables;
// sigma^{-T} via single-wave register Gauss-Jordan (no pivoting; sigma ~ I).
// ---------------------------------------------------------------------------
__global__ __launch_bounds__(512) void prep_kernel(
    const float* __restrict__ ts,
    const float* __restrict__ sigma,
    const float* __restrict__ lpd, const float* __restrict__ lps,
    const float* __restrict__ ltw,
    float* __restrict__ ws)
{
    __shared__ float sg[32][33];
    const int tid = threadIdx.x;

    ws[WS_W + tid] = expf(lpd[tid] + lps[tid] + ltw[tid]);

    if (tid < T_STEPS) {
        float a = ts[tid], b = ts[tid + 1];
        float dt = b - a;
        ws[WS_DT + tid]  = dt;
        ws[WS_SDT + tid] = sqrtf(LMBD * dt);
    }

    for (int idx = tid; idx < 1024; idx += 512)
        sg[idx >> 5][idx & 31] = sigma[idx];
    __syncthreads();

    for (int idx = tid; idx < 1024; idx += 512) {
        int i = idx >> 5, j = idx & 31;
        float s = 0.0f;
        #pragma unroll
        for (int k = 0; k < 32; ++k) s += sg[i][k] * sg[j][k];
        ws[WS_A + idx] = s;
    }

    if (tid < 64) {
        const int l = tid;
        float col[32];
        #pragma unroll
        for (int r = 0; r < 32; ++r) {
            float v = sg[r][l & 31];
            col[r] = (l < 32) ? v : ((r == (l - 32)) ? 1.0f : 0.0f);
        }
        #pragma unroll
        for (int k = 0; k < 32; ++k) {
            float pinv = 1.0f / __shfl(col[k], k);
            col[k] *= pinv;
            #pragma unroll
            for (int r = 0; r < 32; ++r) {
                if (r == k) continue;
                float f = __shfl(col[r], k);
                col[r] -= f * col[k];
            }
        }
        if (l >= 32) {   // lane 32+c holds sigma^{-1} col c; Minv[i][k]=inv[k][i]
            #pragma unroll
            for (int r = 0; r < 32; ++r)
                ws[WS_MINV + (l - 32) * 32 + r] = col[r];
        }
    }
}

// ---------------------------------------------------------------------------
// Kernel 2 (v-precompute): v[t,b] = Minv * ( -sqrt(LMBD*dt)*n - dt*ctl ).
// Pure BW-bound GEMM-shaped pass: 26 MB in, 13 MB out. Block = 8 (t,b) units.
// ---------------------------------------------------------------------------
__global__ __launch_bounds__(256) void v_kernel(
    const float* __restrict__ noises,
    const float* __restrict__ controls,
    float* __restrict__ ws)
{
    __shared__ __align__(16) float wsm[8][36];
    const int tid = threadIdx.x;
    const int uu = tid >> 5, j = tid & 31;
    const int unit = blockIdx.x * 8 + uu;         // unit = t*512 + b
    const int t = unit >> 9;

    const float dt  = ws[WS_DT + t];
    const float sdt = ws[WS_SDT + t];

    const size_t g = (size_t)unit * DD + j;
    float nv = noises[g], cv = controls[g];
    wsm[uu][j] = -sdt * nv - dt * cv;

    // Minv row j (L1-hot)
    float4 mr[8];
    {
        const float4* mp = (const float4*)(ws + WS_MINV + j * 32);
        #pragma unroll
        for (int c = 0; c < 8; ++c) mr[c] = mp[c];
    }
    __syncthreads();

    float v = 0.0f;
    {
        const float4* wr = (const float4*)wsm[uu];
        #pragma unroll
        for (int c = 0; c < 8; ++c) {
            float4 a = wr[c];
            v += mr[c].x * a.x + mr[c].y * a.y + mr[c].z * a.z + mr[c].w * a.w;
        }
    }
    ws[WS_V + g] = v;
}

// ---------------------------------------------------------------------------
// Kernel 3 (stream): 256-thr block = 4 INDEPENDENT waves, each one (b, chunk).
// Barrier-free. Lane l: j = l&31 (component), cg = l&7 (4-col group),
// rg = l>>3 (row-group: owns rows rg+8s of the nb tile).
// Per t: y = P + V;  row-dots of nb (coalesced 1KiB loads) with preloaded v4;
// octet reduce + regather -> pc; P += dt*f + pc; M += y y^T (16 regs).
// Chunk epilogue: m = <A,M>; write P (c-total), Y, m.
// ---------------------------------------------------------------------------
__global__ __launch_bounds__(256) void stream_kernel(
    const float* __restrict__ nabla_f,
    const float* __restrict__ nabla_V,
    const float* __restrict__ nabla_b,
    float* __restrict__ ws)
{
    const int tid = threadIdx.x;
    const int wv  = tid >> 6;
    const int l   = tid & 63;
    const int U   = blockIdx.x * 4 + wv;   // unit id
    const int b   = U >> 4;
    const int h   = U & 15;
    const int j   = l & 31;
    const int cg  = l & 7;
    const int rg  = l >> 3;

    const int t0  = (h < 8) ? 13 * h : 104 + 12 * (h - 8);
    const int len = (h < 8) ? 13 : 12;
    const int t1  = t0 + len;

    const float4* nb = (const float4*)nabla_b;

    float P = 0.0f, Yacc = 0.0f;
    float M00=0,M01=0,M02=0,M03=0, M10=0,M11=0,M12=0,M13=0;
    float M20=0,M21=0,M22=0,M23=0, M30=0,M31=0,M32=0,M33=0;

    for (int t = t0; t < t1; ++t) {
        const int base = (t * BB + b) * DD;
        const size_t f4 = (size_t)base * 8;         // float4 index of tile
        float4 n0 = nb[f4 + l];
        float4 n1 = nb[f4 + l + 64];
        float4 n2 = nb[f4 + l + 128];
        float4 n3 = nb[f4 + l + 192];
        float4 v4 = *(const float4*)(ws + WS_V + base + 4 * cg);
        float fj  = nabla_f[base + j];
        float Vj  = nabla_V[base + j];
        float dt  = ws[WS_DT + t];

        float y = P + Vj;                  // uses P(t-1)
        Yacc += y;

        // row-dots: lane owns rows {rg+8s}, cols 4cg..4cg+3
        float d0 = n0.x*v4.x + n0.y*v4.y + n0.z*v4.z + n0.w*v4.w;
        float d1 = n1.x*v4.x + n1.y*v4.y + n1.z*v4.z + n1.w*v4.w;
        float d2 = n2.x*v4.x + n2.y*v4.y + n2.z*v4.z + n2.w*v4.w;
        float d3 = n3.x*v4.x + n3.y*v4.y + n3.z*v4.z + n3.w*v4.w;
        d0 += __shfl_xor(d0,1); d0 += __shfl_xor(d0,2); d0 += __shfl_xor(d0,4);
        d1 += __shfl_xor(d1,1); d1 += __shfl_xor(d1,2); d1 += __shfl_xor(d1,4);
        d2 += __shfl_xor(d2,1); d2 += __shfl_xor(d2,2); d2 += __shfl_xor(d2,4);
        d3 += __shfl_xor(d3,1); d3 += __shfl_xor(d3,2); d3 += __shfl_xor(d3,4);
        // regather pc_j: src lane 8*(j&7), slot (j>>3)
        float g0 = __shfl(d0, 8 * (l & 7));
        float g1 = __shfl(d1, 8 * (l & 7));
        float g2 = __shfl(d2, 8 * (l & 7));
        float g3 = __shfl(d3, 8 * (l & 7));
        const int slot = (l >> 3) & 3;
        float pA = (slot & 1) ? g1 : g0;
        float pB = (slot & 1) ? g3 : g2;
        float pc = (slot & 2) ? pB : pA;

        P += dt * fj + pc;

        // M[rowset][colgrp] += y_r * y_c
        float yr0 = __shfl(y, rg + 0);
        float yr1 = __shfl(y, rg + 8);
        float yr2 = __shfl(y, rg + 16);
        float yr3 = __shfl(y, rg + 24);
        float yc0 = __shfl(y, 4 * cg + 0);
        float yc1 = __shfl(y, 4 * cg + 1);
        float yc2 = __shfl(y, 4 * cg + 2);
        float yc3 = __shfl(y, 4 * cg + 3);
        M00 += yr0*yc0; M01 += yr0*yc1; M02 += yr0*yc2; M03 += yr0*yc3;
        M10 += yr1*yc0; M11 += yr1*yc1; M12 += yr1*yc2; M13 += yr1*yc3;
        M20 += yr2*yc0; M21 += yr2*yc1; M22 += yr2*yc2; M23 += yr2*yc3;
        M30 += yr3*yc0; M31 += yr3*yc1; M32 += yr3*yc2; M33 += yr3*yc3;
    }

    // tail: t = 200 belongs to last chunk: y(200) = P + V(200)
    if (h == NCH - 1) {
        float Vt = nabla_V[((size_t)T_STEPS * BB + b) * DD + j];
        float y = P + Vt;
        Yacc += y;
        float yr0 = __shfl(y, rg + 0);
        float yr1 = __shfl(y, rg + 8);
        float yr2 = __shfl(y, rg + 16);
        float yr3 = __shfl(y, rg + 24);
        float yc0 = __shfl(y, 4 * cg + 0);
        float yc1 = __shfl(y, 4 * cg + 1);
        float yc2 = __shfl(y, 4 * cg + 2);
        float yc3 = __shfl(y, 4 * cg + 3);
        M00 += yr0*yc0; M01 += yr0*yc1; M02 += yr0*yc2; M03 += yr0*yc3;
        M10 += yr1*yc0; M11 += yr1*yc1; M12 += yr1*yc2; M13 += yr1*yc3;
        M20 += yr2*yc0; M21 += yr2*yc1; M22 += yr2*yc2; M23 += yr2*yc3;
        M30 += yr3*yc0; M31 += yr3*yc1; M32 += yr3*yc2; M33 += yr3*yc3;
    }

    // epilogue: m = <A, M>  (lane covers rows rg+8s x cols 4cg+k, each once)
    float mpart;
    {
        const float* Ab = ws + WS_A;
        float4 A0 = *(const float4*)(Ab + (rg +  0) * 32 + 4 * cg);
        float4 A1 = *(const float4*)(Ab + (rg +  8) * 32 + 4 * cg);
        float4 A2 = *(const float4*)(Ab + (rg + 16) * 32 + 4 * cg);
        float4 A3 = *(const float4*)(Ab + (rg + 24) * 32 + 4 * cg);
        mpart = M00*A0.x + M01*A0.y + M02*A0.z + M03*A0.w
              + M10*A1.x + M11*A1.y + M12*A1.z + M13*A1.w
              + M20*A2.x + M21*A2.y + M22*A2.z + M23*A2.w
              + M30*A3.x + M31*A3.y + M32*A3.z + M33*A3.w;
    }
    mpart += __shfl_xor(mpart, 1);
    mpart += __shfl_xor(mpart, 2);
    mpart += __shfl_xor(mpart, 4);
    mpart += __shfl_xor(mpart, 8);
    mpart += __shfl_xor(mpart, 16);
    mpart += __shfl_xor(mpart, 32);

    if ((l >> 5) == 0) {
        ws[WS_CT + (b * NCH + h) * 32 + j] = P;
        ws[WS_Y  + (b * NCH + h) * 32 + j] = Yacc;
    }
    if (l == 0) ws[WS_M + b * NCH + h] = mpart;
}

// ---------------------------------------------------------------------------
// Kernel 4 (combine): per b, resolve cross-chunk prefix algebra:
//   S = g + sum_h CT_h ; C_h = prefix ; S'_h = S - C_h
//   loss_b = w_b * sum_h [ n_h S'^T A S' - 2 S'^T A Y_h + m_h ]
// ---------------------------------------------------------------------------
__global__ __launch_bounds__(256) void combine_kernel(
    const float* __restrict__ nabla_g,
    float* __restrict__ ws)
{
    __shared__ float ct[NCH][32], Yl[NCH][32];
    __shared__ float Sv[32], Cp[32];
    __shared__ __align__(16) float sp[32];
    __shared__ float red[32];

    const int b   = blockIdx.x;
    const int tid = threadIdx.x;
    const int r   = tid >> 3;
    const int q   = tid & 7;

    for (int idx = tid; idx < NCH * 32; idx += 256) {
        int hh = idx >> 5, i = idx & 31;
        ct[hh][i] = ws[WS_CT + (b * NCH + hh) * 32 + i];
        Yl[hh][i] = ws[WS_Y  + (b * NCH + hh) * 32 + i];
    }
    if (tid < 32) Cp[tid] = 0.0f;
    __syncthreads();
    if (tid < 32) {
        float s = nabla_g[b * 32 + tid];
        #pragma unroll
        for (int hh = 0; hh < NCH; ++hh) s += ct[hh][tid];
        Sv[tid] = s;
    }

    float acc = 0.0f;
    float4 A4 = *(const float4*)(ws + WS_A + r * 32 + 4 * q);
    for (int hh = 0; hh < NCH; ++hh) {
        __syncthreads();
        if (tid < 32) sp[tid] = Sv[tid] - Cp[tid];
        __syncthreads();
        float4 s4 = *(const float4*)&sp[4 * q];
        float as = A4.x * s4.x + A4.y * s4.y + A4.z * s4.z + A4.w * s4.w;
        as += __shfl_xor(as, 1);
        as += __shfl_xor(as, 2);
        as += __shfl_xor(as, 4);
        float nh = ((hh < 8) ? 13.0f : 12.0f) + ((hh == NCH - 1) ? 1.0f : 0.0f);
        if (q == 0) acc += as * (nh * sp[r] - 2.0f * Yl[hh][r]);
        if (tid < 32) Cp[tid] += ct[hh][tid];
    }
    __syncthreads();
    if (q == 0) red[r] = acc;
    __syncthreads();
    if (tid == 0) {
        float s = 0.0f;
        #pragma unroll
        for (int i = 0; i < 32; ++i) s += red[i];
        #pragma unroll
        for (int hh = 0; hh < NCH; ++hh) s += ws[WS_M + b * NCH + hh];
        ws[WS_PART + b] = ws[WS_W + b] * s;
    }
}

// ---------------------------------------------------------------------------
// Kernel 5: deterministic final reduction
// ---------------------------------------------------------------------------
__global__ __launch_bounds__(512) void reduce_kernel(
    const float* __restrict__ ws, float* __restrict__ out)
{
    __shared__ float r[512];
    const int tid = threadIdx.x;
    r[tid] = ws[WS_PART + tid];
    __syncthreads();
    for (int st = 256; st > 0; st >>= 1) {
        if (tid < st) r[tid] += r[tid + st];
        __syncthreads();
    }
    if (tid == 0) out[0] = r[0] * (1.0f / (201.0f * 512.0f));
}

extern "C" void kernel_launch(void* const* d_in, const int* in_sizes, int n_in,
                              void* d_out, int out_size, void* d_ws, size_t ws_size,
                              hipStream_t stream) {
    (void)in_sizes; (void)n_in; (void)out_size; (void)ws_size;
    const float* ts       = (const float*)d_in[0];
    const float* noises   = (const float*)d_in[2];
    const float* controls = (const float*)d_in[3];
    const float* nabla_V  = (const float*)d_in[4];
    const float* nabla_f  = (const float*)d_in[5];
    const float* nabla_b  = (const float*)d_in[6];
    const float* nabla_g  = (const float*)d_in[7];
    const float* sigma    = (const float*)d_in[8];
    const float* lpd      = (const float*)d_in[9];
    const float* lps      = (const float*)d_in[10];
    const float* ltw      = (const float*)d_in[11];
    float* ws  = (float*)d_ws;
    float* out = (float*)d_out;

    prep_kernel<<<1, 512, 0, stream>>>(ts, sigma, lpd, lps, ltw, ws);
    v_kernel<<<(T_STEPS * BB) / 8, 256, 0, stream>>>(noises, controls, ws);
    stream_kernel<<<(BB * NCH) / 4, 256, 0, stream>>>(nabla_f, nabla_V,
                                                      nabla_b, ws);
    combine_kernel<<<BB, 256, 0, stream>>>(nabla_g, ws);
    reduce_kernel<<<1, 512, 0, stream>>>(ws, out);
}

// Round 7
// 158.871 us; speedup vs baseline: 1.0558x; 1.0558x over previous
//
#include <hip/hip_runtime.h>
#include <math.h>

#define T_STEPS 200
#define BB 512
#define DD 32
#define LMBD 1.0f
#define NCH 8          // t-chunks per b (one wave each), CHT=25
#define CHT 25

// ws layout (floats)
#define WS_MINV 0                  // sigma^{-T} [i][k], 1024
#define WS_A    1024               // A = sigma sigma^T, 1024
#define WS_W    2048               // weight[512]
#define WS_PART 2560               // per-b partials [512]
#define WS_DT   3072               // dt[200]
#define WS_SDT  3328               // sqrt(LMBD*dt)[200]
#define WS_V    4096               // v[200][512][32] = 3,276,800
#define WS_CT   3280896            // chunk c-totals [512][8][32]
#define WS_Y    3411968            // chunk Y [512][8][32]
#define WS_M    3543040            // chunk <A,M> scalars [512][8]

// ---------------------------------------------------------------------------
// Kernel 1: prep. weight = exp(lpd+lps+ltw); A = sigma sigma^T; dt/sdt tables;
// sigma^{-T} via single-wave register Gauss-Jordan (no pivoting; sigma ~ I).
// ---------------------------------------------------------------------------
__global__ __launch_bounds__(512) void prep_kernel(
    const float* __restrict__ ts,
    const float* __restrict__ sigma,
    const float* __restrict__ lpd, const float* __restrict__ lps,
    const float* __restrict__ ltw,
    float* __restrict__ ws)
{
    __shared__ float sg[32][33];
    const int tid = threadIdx.x;

    ws[WS_W + tid] = expf(lpd[tid] + lps[tid] + ltw[tid]);

    if (tid < T_STEPS) {
        float a = ts[tid], b = ts[tid + 1];
        float dt = b - a;
        ws[WS_DT + tid]  = dt;
        ws[WS_SDT + tid] = sqrtf(LMBD * dt);
    }

    for (int idx = tid; idx < 1024; idx += 512)
        sg[idx >> 5][idx & 31] = sigma[idx];
    __syncthreads();

    for (int idx = tid; idx < 1024; idx += 512) {
        int i = idx >> 5, j = idx & 31;
        float s = 0.0f;
        #pragma unroll
        for (int k = 0; k < 32; ++k) s += sg[i][k] * sg[j][k];
        ws[WS_A + idx] = s;
    }

    if (tid < 64) {
        const int l = tid;
        float col[32];
        #pragma unroll
        for (int r = 0; r < 32; ++r) {
            float v = sg[r][l & 31];
            col[r] = (l < 32) ? v : ((r == (l - 32)) ? 1.0f : 0.0f);
        }
        #pragma unroll
        for (int k = 0; k < 32; ++k) {
            float pinv = 1.0f / __shfl(col[k], k);
            col[k] *= pinv;
            #pragma unroll
            for (int r = 0; r < 32; ++r) {
                if (r == k) continue;
                float f = __shfl(col[r], k);
                col[r] -= f * col[k];
            }
        }
        if (l >= 32) {   // lane 32+c holds sigma^{-1} col c; Minv[i][k]=inv[k][i]
            #pragma unroll
            for (int r = 0; r < 32; ++r)
                ws[WS_MINV + (l - 32) * 32 + r] = col[r];
        }
    }
}

// ---------------------------------------------------------------------------
// Kernel 2 (v-precompute): v[t,b] = Minv * ( -sqrt(LMBD*dt)*n - dt*ctl ).
// Pure BW-bound pass: 26 MB in, 13 MB out.
// ---------------------------------------------------------------------------
__global__ __launch_bounds__(256) void v_kernel(
    const float* __restrict__ noises,
    const float* __restrict__ controls,
    float* __restrict__ ws)
{
    __shared__ __align__(16) float wsm[8][36];
    const int tid = threadIdx.x;
    const int uu = tid >> 5, j = tid & 31;
    const int unit = blockIdx.x * 8 + uu;         // unit = t*512 + b
    const int t = unit >> 9;

    const float dt  = ws[WS_DT + t];
    const float sdt = ws[WS_SDT + t];

    const size_t g = (size_t)unit * DD + j;
    float nv = noises[g], cv = controls[g];
    wsm[uu][j] = -sdt * nv - dt * cv;

    float4 mr[8];
    {
        const float4* mp = (const float4*)(ws + WS_MINV + j * 32);
        #pragma unroll
        for (int c = 0; c < 8; ++c) mr[c] = mp[c];
    }
    __syncthreads();

    float v = 0.0f;
    {
        const float4* wr = (const float4*)wsm[uu];
        #pragma unroll
        for (int c = 0; c < 8; ++c) {
            float4 a = wr[c];
            v += mr[c].x * a.x + mr[c].y * a.y + mr[c].z * a.z + mr[c].w * a.w;
        }
    }
    ws[WS_V + g] = v;
}

// ---------------------------------------------------------------------------
// Kernel 3 (stream): 256-thr block = 4 INDEPENDENT waves, each one (b, chunk).
// Barrier-free, 1-deep REGISTER double-buffer on all loop inputs (nb tile,
// v4, f, V) so HBM latency hides under the previous iteration's compute.
// Lane l: j = l&31 (component), cg = l&7 (4-col group), rg = l>>3 (row group).
// Per t: y = P + V; nb row-dots with v4; octet reduce + regather -> pc;
// P += dt*f + pc; M += y y^T (16 regs). Epilogue: m = <A,M>; write P, Y, m.
// ---------------------------------------------------------------------------
__global__ __launch_bounds__(256) void stream_kernel(
    const float* __restrict__ nabla_f,
    const float* __restrict__ nabla_V,
    const float* __restrict__ nabla_b,
    float* __restrict__ ws)
{
    const int tid = threadIdx.x;
    const int wv  = tid >> 6;
    const int l   = tid & 63;
    const int U   = blockIdx.x * 4 + wv;   // unit id
    const int b   = U >> 3;
    const int h   = U & 7;
    const int j   = l & 31;
    const int cg  = l & 7;
    const int rg  = l >> 3;

    const int t0 = h * CHT, t1 = t0 + CHT;

    const float4* nb = (const float4*)nabla_b;

    // prologue: load t0
    int base = (t0 * BB + b) * DD;
    size_t f4 = (size_t)base * 8;
    float4 n0 = nb[f4 + l];
    float4 n1 = nb[f4 + l + 64];
    float4 n2 = nb[f4 + l + 128];
    float4 n3 = nb[f4 + l + 192];
    float4 v4 = *(const float4*)(ws + WS_V + base + 4 * cg);
    float  fj = nabla_f[base + j];
    float  Vj = nabla_V[base + j];

    float P = 0.0f, Yacc = 0.0f;
    float M00=0,M01=0,M02=0,M03=0, M10=0,M11=0,M12=0,M13=0;
    float M20=0,M21=0,M22=0,M23=0, M30=0,M31=0,M32=0,M33=0;

    for (int t = t0; t < t1; ++t) {
        // issue next-iteration prefetch (clamped; barrier-free -> in flight)
        const int tn = (t + 1 < t1) ? t + 1 : t;
        const int basen = (tn * BB + b) * DD;
        const size_t f4n = (size_t)basen * 8;
        float4 m0 = nb[f4n + l];
        float4 m1 = nb[f4n + l + 64];
        float4 m2 = nb[f4n + l + 128];
        float4 m3 = nb[f4n + l + 192];
        float4 v4n = *(const float4*)(ws + WS_V + basen + 4 * cg);
        float  fjn = nabla_f[basen + j];
        float  Vjn = nabla_V[basen + j];

        const float dt = ws[WS_DT + t];

        float y = P + Vj;                  // uses P(t-1)
        Yacc += y;

        // row-dots: lane owns rows {rg+8s}, cols 4cg..4cg+3
        float d0 = n0.x*v4.x + n0.y*v4.y + n0.z*v4.z + n0.w*v4.w;
        float d1 = n1.x*v4.x + n1.y*v4.y + n1.z*v4.z + n1.w*v4.w;
        float d2 = n2.x*v4.x + n2.y*v4.y + n2.z*v4.z + n2.w*v4.w;
        float d3 = n3.x*v4.x + n3.y*v4.y + n3.z*v4.z + n3.w*v4.w;
        d0 += __shfl_xor(d0,1); d0 += __shfl_xor(d0,2); d0 += __shfl_xor(d0,4);
        d1 += __shfl_xor(d1,1); d1 += __shfl_xor(d1,2); d1 += __shfl_xor(d1,4);
        d2 += __shfl_xor(d2,1); d2 += __shfl_xor(d2,2); d2 += __shfl_xor(d2,4);
        d3 += __shfl_xor(d3,1); d3 += __shfl_xor(d3,2); d3 += __shfl_xor(d3,4);
        // regather pc_j: src lane 8*(j&7), slot (j>>3)
        float g0 = __shfl(d0, 8 * (l & 7));
        float g1 = __shfl(d1, 8 * (l & 7));
        float g2 = __shfl(d2, 8 * (l & 7));
        float g3 = __shfl(d3, 8 * (l & 7));
        const int slot = (l >> 3) & 3;
        float pA = (slot & 1) ? g1 : g0;
        float pB = (slot & 1) ? g3 : g2;
        float pc = (slot & 2) ? pB : pA;

        P += dt * fj + pc;

        // M[rowset][colgrp] += y_r * y_c
        float yr0 = __shfl(y, rg + 0);
        float yr1 = __shfl(y, rg + 8);
        float yr2 = __shfl(y, rg + 16);
        float yr3 = __shfl(y, rg + 24);
        float yc0 = __shfl(y, 4 * cg + 0);
        float yc1 = __shfl(y, 4 * cg + 1);
        float yc2 = __shfl(y, 4 * cg + 2);
        float yc3 = __shfl(y, 4 * cg + 3);
        M00 += yr0*yc0; M01 += yr0*yc1; M02 += yr0*yc2; M03 += yr0*yc3;
        M10 += yr1*yc0; M11 += yr1*yc1; M12 += yr1*yc2; M13 += yr1*yc3;
        M20 += yr2*yc0; M21 += yr2*yc1; M22 += yr2*yc2; M23 += yr2*yc3;
        M30 += yr3*yc0; M31 += yr3*yc1; M32 += yr3*yc2; M33 += yr3*yc3;

        // rotate prefetch
        n0 = m0; n1 = m1; n2 = m2; n3 = m3; v4 = v4n; fj = fjn; Vj = Vjn;
    }

    // tail: t = 200 belongs to last chunk: y(200) = P + V(200)
    if (h == NCH - 1) {
        float Vt = nabla_V[((size_t)T_STEPS * BB + b) * DD + j];
        float y = P + Vt;
        Yacc += y;
        float yr0 = __shfl(y, rg + 0);
        float yr1 = __shfl(y, rg + 8);
        float yr2 = __shfl(y, rg + 16);
        float yr3 = __shfl(y, rg + 24);
        float yc0 = __shfl(y, 4 * cg + 0);
        float yc1 = __shfl(y, 4 * cg + 1);
        float yc2 = __shfl(y, 4 * cg + 2);
        float yc3 = __shfl(y, 4 * cg + 3);
        M00 += yr0*yc0; M01 += yr0*yc1; M02 += yr0*yc2; M03 += yr0*yc3;
        M10 += yr1*yc0; M11 += yr1*yc1; M12 += yr1*yc2; M13 += yr1*yc3;
        M20 += yr2*yc0; M21 += yr2*yc1; M22 += yr2*yc2; M23 += yr2*yc3;
        M30 += yr3*yc0; M31 += yr3*yc1; M32 += yr3*yc2; M33 += yr3*yc3;
    }

    // epilogue: m = <A, M>  (lane covers rows rg+8s x cols 4cg+k, each once)
    float mpart;
    {
        const float* Ab = ws + WS_A;
        float4 A0 = *(const float4*)(Ab + (rg +  0) * 32 + 4 * cg);
        float4 A1 = *(const float4*)(Ab + (rg +  8) * 32 + 4 * cg);
        float4 A2 = *(const float4*)(Ab + (rg + 16) * 32 + 4 * cg);
        float4 A3 = *(const float4*)(Ab + (rg + 24) * 32 + 4 * cg);
        mpart = M00*A0.x + M01*A0.y + M02*A0.z + M03*A0.w
              + M10*A1.x + M11*A1.y + M12*A1.z + M13*A1.w
              + M20*A2.x + M21*A2.y + M22*A2.z + M23*A2.w
              + M30*A3.x + M31*A3.y + M32*A3.z + M33*A3.w;
    }
    mpart += __shfl_xor(mpart, 1);
    mpart += __shfl_xor(mpart, 2);
    mpart += __shfl_xor(mpart, 4);
    mpart += __shfl_xor(mpart, 8);
    mpart += __shfl_xor(mpart, 16);
    mpart += __shfl_xor(mpart, 32);

    if ((l >> 5) == 0) {
        ws[WS_CT + (b * NCH + h) * 32 + j] = P;
        ws[WS_Y  + (b * NCH + h) * 32 + j] = Yacc;
    }
    if (l == 0) ws[WS_M + b * NCH + h] = mpart;
}

// ---------------------------------------------------------------------------
// Kernel 4 (combine): per b, resolve cross-chunk prefix algebra:
//   S = g + sum_h CT_h ; C_h = prefix ; S'_h = S - C_h
//   loss_b = w_b * sum_h [ n_h S'^T A S' - 2 S'^T A Y_h + m_h ]
// ---------------------------------------------------------------------------
__global__ __launch_bounds__(256) void combine_kernel(
    const float* __restrict__ nabla_g,
    float* __restrict__ ws)
{
    __shared__ float ct[NCH][32], Yl[NCH][32];
    __shared__ float Sv[32], Cp[32];
    __shared__ __align__(16) float sp[32];
    __shared__ float red[32];

    const int b   = blockIdx.x;
    const int tid = threadIdx.x;
    const int r   = tid >> 3;
    const int q   = tid & 7;

    {
        int hh = tid >> 5, i = tid & 31;   // 256 threads = 8x32 exactly
        ct[hh][i] = ws[WS_CT + (b * NCH + hh) * 32 + i];
        Yl[hh][i] = ws[WS_Y  + (b * NCH + hh) * 32 + i];
    }
    if (tid < 32) Cp[tid] = 0.0f;
    __syncthreads();
    if (tid < 32) {
        float s = nabla_g[b * 32 + tid];
        #pragma unroll
        for (int hh = 0; hh < NCH; ++hh) s += ct[hh][tid];
        Sv[tid] = s;
    }

    float acc = 0.0f;
    float4 A4 = *(const float4*)(ws + WS_A + r * 32 + 4 * q);
    for (int hh = 0; hh < NCH; ++hh) {
        __syncthreads();
        if (tid < 32) sp[tid] = Sv[tid] - Cp[tid];
        __syncthreads();
        float4 s4 = *(const float4*)&sp[4 * q];
        float as = A4.x * s4.x + A4.y * s4.y + A4.z * s4.z + A4.w * s4.w;
        as += __shfl_xor(as, 1);
        as += __shfl_xor(as, 2);
        as += __shfl_xor(as, 4);
        float nh = (hh == NCH - 1) ? (float)(CHT + 1) : (float)CHT;
        if (q == 0) acc += as * (nh * sp[r] - 2.0f * Yl[hh][r]);
        if (tid < 32) Cp[tid] += ct[hh][tid];
    }
    __syncthreads();
    if (q == 0) red[r] = acc;
    __syncthreads();
    if (tid == 0) {
        float s = 0.0f;
        #pragma unroll
        for (int i = 0; i < 32; ++i) s += red[i];
        #pragma unroll
        for (int hh = 0; hh < NCH; ++hh) s += ws[WS_M + b * NCH + hh];
        ws[WS_PART + b] = ws[WS_W + b] * s;
    }
}

// ---------------------------------------------------------------------------
// Kernel 5: deterministic final reduction
// ---------------------------------------------------------------------------
__global__ __launch_bounds__(512) void reduce_kernel(
    const float* __restrict__ ws, float* __restrict__ out)
{
    __shared__ float r[512];
    const int tid = threadIdx.x;
    r[tid] = ws[WS_PART + tid];
    __syncthreads();
    for (int st = 256; st > 0; st >>= 1) {
        if (tid < st) r[tid] += r[tid + st];
        __syncthreads();
    }
    if (tid == 0) out[0] = r[0] * (1.0f / (201.0f * 512.0f));
}

extern "C" void kernel_launch(void* const* d_in, const int* in_sizes, int n_in,
                              void* d_out, int out_size, void* d_ws, size_t ws_size,
                              hipStream_t stream) {
    (void)in_sizes; (void)n_in; (void)out_size; (void)ws_size;
    const float* ts       = (const float*)d_in[0];
    const float* noises   = (const float*)d_in[2];
    const float* controls = (const float*)d_in[3];
    const float* nabla_V  = (const float*)d_in[4];
    const float* nabla_f  = (const float*)d_in[5];
    const float* nabla_b  = (const float*)d_in[6];
    const float* nabla_g  = (const float*)d_in[7];
    const float* sigma    = (const float*)d_in[8];
    const float* lpd      = (const float*)d_in[9];
    const float* lps      = (const float*)d_in[10];
    const float* ltw      = (const float*)d_in[11];
    float* ws  = (float*)d_ws;
    float* out = (float*)d_out;

    prep_kernel<<<1, 512, 0, stream>>>(ts, sigma, lpd, lps, ltw, ws);
    v_kernel<<<(T_STEPS * BB) / 8, 256, 0, stream>>>(noises, controls, ws);
    stream_kernel<<<(BB * NCH) / 4, 256, 0, stream>>>(nabla_f, nabla_V,
                                                      nabla_b, ws);
    combine_kernel<<<BB, 256, 0, stream>>>(nabla_g, ws);
    reduce_kernel<<<1, 512, 0, stream>>>(ws, out);
}

// Round 8
// 156.878 us; speedup vs baseline: 1.0692x; 1.0127x over previous
//
#include <hip/hip_runtime.h>
#include <math.h>

#define T_STEPS 200
#define BB 512
#define DD 32
#define LMBD 1.0f
#define NCH 4          // t-chunks per b (one 256-thr block each)
#define CHT 50

// ws layout (floats)
#define WS_MINV 0                  // sigma^{-T} [i][k], 1024
#define WS_A    1024               // A = sigma sigma^T, 1024
#define WS_W    2048               // weight[512]
#define WS_PART 2560               // per-b partials [512]
#define WS_DT   3072               // dt[200]
#define WS_SDT  3328               // sqrt(LMBD*dt)[200]
#define WS_V    4096               // v[200][512][32] = 3,276,800
#define WS_CT   3280896            // chunk c-totals [512][4][32]
#define WS_Y    3346432            // chunk Y [512][4][32]
#define WS_M    3411968            // chunk <A,M> scalars [512][4]

// ---------------------------------------------------------------------------
// Kernel 1: prep. weight = exp(lpd+lps+ltw); A = sigma sigma^T; dt/sdt tables;
// sigma^{-T} via single-wave register Gauss-Jordan (no pivoting; sigma ~ I).
// ---------------------------------------------------------------------------
__global__ __launch_bounds__(512) void prep_kernel(
    const float* __restrict__ ts,
    const float* __restrict__ sigma,
    const float* __restrict__ lpd, const float* __restrict__ lps,
    const float* __restrict__ ltw,
    float* __restrict__ ws)
{
    __shared__ float sg[32][33];
    const int tid = threadIdx.x;

    ws[WS_W + tid] = expf(lpd[tid] + lps[tid] + ltw[tid]);

    if (tid < T_STEPS) {
        float a = ts[tid], b = ts[tid + 1];
        float dt = b - a;
        ws[WS_DT + tid]  = dt;
        ws[WS_SDT + tid] = sqrtf(LMBD * dt);
    }

    for (int idx = tid; idx < 1024; idx += 512)
        sg[idx >> 5][idx & 31] = sigma[idx];
    __syncthreads();

    for (int idx = tid; idx < 1024; idx += 512) {
        int i = idx >> 5, j = idx & 31;
        float s = 0.0f;
        #pragma unroll
        for (int k = 0; k < 32; ++k) s += sg[i][k] * sg[j][k];
        ws[WS_A + idx] = s;
    }

    if (tid < 64) {
        const int l = tid;
        float col[32];
        #pragma unroll
        for (int r = 0; r < 32; ++r) {
            float v = sg[r][l & 31];
            col[r] = (l < 32) ? v : ((r == (l - 32)) ? 1.0f : 0.0f);
        }
        #pragma unroll
        for (int k = 0; k < 32; ++k) {
            float pinv = 1.0f / __shfl(col[k], k);
            col[k] *= pinv;
            #pragma unroll
            for (int r = 0; r < 32; ++r) {
                if (r == k) continue;
                float f = __shfl(col[r], k);
                col[r] -= f * col[k];
            }
        }
        if (l >= 32) {   // lane 32+c holds sigma^{-1} col c; Minv[i][k]=inv[k][i]
            #pragma unroll
            for (int r = 0; r < 32; ++r)
                ws[WS_MINV + (l - 32) * 32 + r] = col[r];
        }
    }
}

// ---------------------------------------------------------------------------
// Kernel 2 (v-precompute): v[t,b] = Minv * ( -sqrt(LMBD*dt)*n - dt*ctl ).
// Pure BW-bound pass: 26 MB in, 13 MB out.
// ---------------------------------------------------------------------------
__global__ __launch_bounds__(256) void v_kernel(
    const float* __restrict__ noises,
    const float* __restrict__ controls,
    float* __restrict__ ws)
{
    __shared__ __align__(16) float wsm[8][36];
    const int tid = threadIdx.x;
    const int uu = tid >> 5, j = tid & 31;
    const int unit = blockIdx.x * 8 + uu;         // unit = t*512 + b
    const int t = unit >> 9;

    const float dt  = ws[WS_DT + t];
    const float sdt = ws[WS_SDT + t];

    const size_t g = (size_t)unit * DD + j;
    float nv = noises[g], cv = controls[g];
    wsm[uu][j] = -sdt * nv - dt * cv;

    float4 mr[8];
    {
        const float4* mp = (const float4*)(ws + WS_MINV + j * 32);
        #pragma unroll
        for (int c = 0; c < 8; ++c) mr[c] = mp[c];
    }
    __syncthreads();

    float v = 0.0f;
    {
        const float4* wr = (const float4*)wsm[uu];
        #pragma unroll
        for (int c = 0; c < 8; ++c) {
            float4 a = wr[c];
            v += mr[c].x * a.x + mr[c].y * a.y + mr[c].z * a.z + mr[c].w * a.w;
        }
    }
    ws[WS_V + g] = v;
}

// ---------------------------------------------------------------------------
// Kernel 3 (stream): R4 shape — one (chunk h, b) per 256-thr block, 2048
// blocks, ~45 VGPR -> 8 blocks/CU (32 waves/CU). ONE barrier per t.
// Thread (r = tid>>3, q = tid&7): holds nb row r cols 4q..4q+3 (tile load is
// 4KB fully coalesced), M[r][4q..4q+3] in 4 regs; P[r], Y[r] replicated x8.
// Per t: y = P + V (prev P); pc = row-dot via dot4 + 3 shfl_xor; P update;
// yls parity exchange (1 barrier); M += y * y4.  Epilogue: m = <A,M>, write.
// ---------------------------------------------------------------------------
__global__ __launch_bounds__(256) void stream_kernel(
    const float* __restrict__ nabla_f,
    const float* __restrict__ nabla_V,
    const float* __restrict__ nabla_b,
    float* __restrict__ ws)
{
    __shared__ __align__(16) float yls[2][32];
    __shared__ float red[256];

    const int h   = blockIdx.x;        // 0..3
    const int b   = blockIdx.y;        // 0..511
    const int tid = threadIdx.x;
    const int r   = tid >> 3;          // 0..31
    const int q   = tid & 7;           // 0..7

    const int t0 = h * CHT, t1 = t0 + CHT;
    const float4* nb = (const float4*)nabla_b;

    // prologue: load t0 into current regs
    int base = (t0 * BB + b) * DD;
    float4 nbC = nb[(size_t)base * 8 + tid];
    float4 v4C = *(const float4*)(ws + WS_V + base + 4 * q);
    float  fC  = nabla_f[base + r];
    float  VC  = nabla_V[base + r];

    float P = 0.0f, Yacc = 0.0f;
    float a0 = 0.f, a1 = 0.f, a2 = 0.f, a3 = 0.f;

    for (int t = t0; t < t1; ++t) {
        // 1-deep register prefetch of t+1 (clamped)
        const int tn = (t + 1 < t1) ? t + 1 : t;
        const int basen = (tn * BB + b) * DD;
        float4 nbN = nb[(size_t)basen * 8 + tid];
        float4 v4N = *(const float4*)(ws + WS_V + basen + 4 * q);
        float  fN  = nabla_f[basen + r];
        float  VN  = nabla_V[basen + r];

        const float dt = ws[WS_DT + t];
        const int p = t & 1;

        // y uses P(t-1)
        float y = P + VC;
        Yacc += y;
        if (q == 0) yls[p][r] = y;

        // pc = <nb row r, v>: dot4 + octet reduce (lanes 8r..8r+7)
        float pc = nbC.x * v4C.x + nbC.y * v4C.y + nbC.z * v4C.z + nbC.w * v4C.w;
        pc += __shfl_xor(pc, 1);
        pc += __shfl_xor(pc, 2);
        pc += __shfl_xor(pc, 4);
        P += dt * fC + pc;

        __syncthreads();   // yls[p] visible to all waves

        float4 y4 = *(const float4*)&yls[p][4 * q];
        a0 += y * y4.x; a1 += y * y4.y; a2 += y * y4.z; a3 += y * y4.w;

        // rotate prefetch
        nbC = nbN; v4C = v4N; fC = fN; VC = VN;
    }

    // tail: t = 200 belongs to last chunk: y(200) = P + V(200)
    if (h == NCH - 1) {
        float Vt = nabla_V[((size_t)T_STEPS * BB + b) * DD + r];
        float y = P + Vt;
        Yacc += y;
        if (q == 0) yls[0][r] = y;   // last loop read of yls[0] was t=198; safe
        __syncthreads();
        float4 y4 = *(const float4*)&yls[0][4 * q];
        a0 += y * y4.x; a1 += y * y4.y; a2 += y * y4.z; a3 += y * y4.w;
    }

    // epilogue: m = <A, M>, block reduce; write CT, Y, m
    float4 A4 = *(const float4*)(ws + WS_A + r * 32 + 4 * q);
    float mpart = a0 * A4.x + a1 * A4.y + a2 * A4.z + a3 * A4.w;
    __syncthreads();
    red[tid] = mpart;
    __syncthreads();
    for (int st = 128; st > 0; st >>= 1) {
        if (tid < st) red[tid] += red[tid + st];
        __syncthreads();
    }
    if (q == 0) {
        ws[WS_CT + (b * NCH + h) * 32 + r] = P;
        ws[WS_Y  + (b * NCH + h) * 32 + r] = Yacc;
    }
    if (tid == 0) ws[WS_M + b * NCH + h] = red[0];
}

// ---------------------------------------------------------------------------
// Kernel 4 (combine): per b, resolve cross-chunk prefix algebra:
//   S = g + sum_h CT_h ; C_h = prefix ; S'_h = S - C_h
//   loss_b = w_b * sum_h [ n_h S'^T A S' - 2 S'^T A Y_h + m_h ]
// ---------------------------------------------------------------------------
__global__ __launch_bounds__(256) void combine_kernel(
    const float* __restrict__ nabla_g,
    float* __restrict__ ws)
{
    __shared__ float ct[NCH][32], Yl[NCH][32];
    __shared__ float Sv[32], Cp[32];
    __shared__ __align__(16) float sp[32];
    __shared__ float red[32];

    const int b   = blockIdx.x;
    const int tid = threadIdx.x;
    const int r   = tid >> 3;
    const int q   = tid & 7;

    if (tid < NCH * 32) {
        int hh = tid >> 5, i = tid & 31;
        ct[hh][i] = ws[WS_CT + (b * NCH + hh) * 32 + i];
        Yl[hh][i] = ws[WS_Y  + (b * NCH + hh) * 32 + i];
    }
    if (tid < 32) Cp[tid] = 0.0f;
    __syncthreads();
    if (tid < 32) {
        float s = nabla_g[b * 32 + tid];
        #pragma unroll
        for (int hh = 0; hh < NCH; ++hh) s += ct[hh][tid];
        Sv[tid] = s;
    }

    float acc = 0.0f;
    float4 A4 = *(const float4*)(ws + WS_A + r * 32 + 4 * q);
    for (int hh = 0; hh < NCH; ++hh) {
        __syncthreads();
        if (tid < 32) sp[tid] = Sv[tid] - Cp[tid];
        __syncthreads();
        float4 s4 = *(const float4*)&sp[4 * q];
        float as = A4.x * s4.x + A4.y * s4.y + A4.z * s4.z + A4.w * s4.w;
        as += __shfl_xor(as, 1);
        as += __shfl_xor(as, 2);
        as += __shfl_xor(as, 4);
        float nh = (hh == NCH - 1) ? (float)(CHT + 1) : (float)CHT;
        if (q == 0) acc += as * (nh * sp[r] - 2.0f * Yl[hh][r]);
        if (tid < 32) Cp[tid] += ct[hh][tid];
    }
    __syncthreads();
    if (q == 0) red[r] = acc;
    __syncthreads();
    if (tid == 0) {
        float s = 0.0f;
        #pragma unroll
        for (int i = 0; i < 32; ++i) s += red[i];
        #pragma unroll
        for (int hh = 0; hh < NCH; ++hh) s += ws[WS_M + b * NCH + hh];
        ws[WS_PART + b] = ws[WS_W + b] * s;
    }
}

// ---------------------------------------------------------------------------
// Kernel 5: deterministic final reduction
// ---------------------------------------------------------------------------
__global__ __launch_bounds__(512) void reduce_kernel(
    const float* __restrict__ ws, float* __restrict__ out)
{
    __shared__ float r[512];
    const int tid = threadIdx.x;
    r[tid] = ws[WS_PART + tid];
    __syncthreads();
    for (int st = 256; st > 0; st >>= 1) {
        if (tid < st) r[tid] += r[tid + st];
        __syncthreads();
    }
    if (tid == 0) out[0] = r[0] * (1.0f / (201.0f * 512.0f));
}

extern "C" void kernel_launch(void* const* d_in, const int* in_sizes, int n_in,
                              void* d_out, int out_size, void* d_ws, size_t ws_size,
                              hipStream_t stream) {
    (void)in_sizes; (void)n_in; (void)out_size; (void)ws_size;
    const float* ts       = (const float*)d_in[0];
    const float* noises   = (const float*)d_in[2];
    const float* controls = (const float*)d_in[3];
    const float* nabla_V  = (const float*)d_in[4];
    const float* nabla_f  = (const float*)d_in[5];
    const float* nabla_b  = (const float*)d_in[6];
    const float* nabla_g  = (const float*)d_in[7];
    const float* sigma    = (const float*)d_in[8];
    const float* lpd      = (const float*)d_in[9];
    const float* lps      = (const float*)d_in[10];
    const float* ltw      = (const float*)d_in[11];
    float* ws  = (float*)d_ws;
    float* out = (float*)d_out;

    prep_kernel<<<1, 512, 0, stream>>>(ts, sigma, lpd, lps, ltw, ws);
    v_kernel<<<(T_STEPS * BB) / 8, 256, 0, stream>>>(noises, controls, ws);
    stream_kernel<<<dim3(NCH, BB), 256, 0, stream>>>(nabla_f, nabla_V,
                                                     nabla_b, ws);
    combine_kernel<<<BB, 256, 0, stream>>>(nabla_g, ws);
    reduce_kernel<<<1, 512, 0, stream>>>(ws, out);
}

// Round 9
// 112.051 us; speedup vs baseline: 1.4970x; 1.4001x over previous
//
#include <hip/hip_runtime.h>
#include <math.h>

#define T_STEPS 200
#define BB 512
#define DD 32
#define LMBD 1.0f
#define NCH 4          // t-chunks per b
#define CHT 50         // t per chunk

// ws layout (floats)
#define WS_MINV 0                  // sigma^{-T} [i][k], 1024
#define WS_A    1024               // A = sigma sigma^T, 1024
#define WS_W    2048               // weight[512]
#define WS_PART 2560               // per-b partials [512]
#define WS_CT   3072               // chunk c-totals [512][4][32]
#define WS_Y    (3072 + 65536)     // chunk Y [512][4][32]
#define WS_M    (3072 + 131072)    // chunk <A,M> scalars [512][4]

// ---------------------------------------------------------------------------
// Kernel 1: prep. weight = exp(lpd+lps+ltw); A = sigma sigma^T;
// sigma^{-T} via single-wave register Gauss-Jordan (no pivoting; sigma ~ I).
// ---------------------------------------------------------------------------
__global__ __launch_bounds__(512) void prep_kernel(
    const float* __restrict__ sigma,
    const float* __restrict__ lpd, const float* __restrict__ lps,
    const float* __restrict__ ltw,
    float* __restrict__ ws)
{
    __shared__ float sg[32][33];
    const int tid = threadIdx.x;

    ws[WS_W + tid] = expf(lpd[tid] + lps[tid] + ltw[tid]);

    for (int idx = tid; idx < 1024; idx += 512)
        sg[idx >> 5][idx & 31] = sigma[idx];
    __syncthreads();

    for (int idx = tid; idx < 1024; idx += 512) {
        int i = idx >> 5, j = idx & 31;
        float s = 0.0f;
        #pragma unroll
        for (int k = 0; k < 32; ++k) s += sg[i][k] * sg[j][k];
        ws[WS_A + idx] = s;
    }

    if (tid < 64) {
        const int l = tid;
        float col[32];
        #pragma unroll
        for (int r = 0; r < 32; ++r) {
            float v = sg[r][l & 31];
            col[r] = (l < 32) ? v : ((r == (l - 32)) ? 1.0f : 0.0f);
        }
        #pragma unroll
        for (int k = 0; k < 32; ++k) {
            float pinv = 1.0f / __shfl(col[k], k);
            col[k] *= pinv;
            #pragma unroll
            for (int r = 0; r < 32; ++r) {
                if (r == k) continue;
                float f = __shfl(col[r], k);
                col[r] -= f * col[k];
            }
        }
        if (l >= 32) {   // lane 32+c holds sigma^{-1} col c; Minv[i][k]=inv[k][i]
            #pragma unroll
            for (int r = 0; r < 32; ++r)
                ws[WS_MINV + (l - 32) * 32 + r] = col[r];
        }
    }
}

// ---------------------------------------------------------------------------
// Kernel 2 (stream): R4 champion structure, 3->2 barriers per t.
// Block = (chunk h, b). Streams nabla_b once; per t:
//   v = Minv * (-sqrt(dt)*n - dt*ctl)       (octet dot + shfl reduce)
//   y(t) = P(t-1) + V(t);  c_t = dt*f + nb.v;  P += c_t
//   Y += y;  M += y y^T   (thread (r,q) holds M[r][4q..4q+3])
// Staging of next-t smalls moved into the y-phase (parity-disjoint from all
// buf[p] reads; barrier 2 + next-iter barrier 1 fence next-iter readers), so
// barrier 3 is deleted. One extra barrier after the loop protects the tail.
// ---------------------------------------------------------------------------
__global__ __launch_bounds__(256) void stream_kernel(
    const float* __restrict__ ts,
    const float* __restrict__ noises,
    const float* __restrict__ controls,
    const float* __restrict__ nabla_f,
    const float* __restrict__ nabla_V,
    const float* __restrict__ nabla_b,
    float* __restrict__ ws)
{
    __shared__ float ts_l[52];
    __shared__ __align__(16) float buf[2][4][32];   // [parity][n,ctl,f,V][i]
    __shared__ __align__(16) float vls[32];
    __shared__ __align__(16) float yls[32];
    __shared__ float red[256];

    const int h   = blockIdx.x;        // 0..3
    const int b   = blockIdx.y;        // 0..511
    const int tid = threadIdx.x;
    const int r   = tid >> 3;          // 0..31 (row / i)
    const int q   = tid & 7;           // 0..7  (4-col group)
    const int w   = tid >> 6;          // wave 0..3
    const int lane = tid & 63;

    const int t0 = h * CHT, t1 = t0 + CHT;

    // per-wave small-array pointer (wave-uniform)
    const float* sp_w = (w == 0) ? noises : (w == 1) ? controls
                       : (w == 2) ? nabla_f : nabla_V;

    // stage ts[t0 .. t0+50]
    if (tid < 51) ts_l[tid] = ts[t0 + tid];
    // stage smalls for t0
    if (lane < 32) buf[0][w][lane] = sp_w[((size_t)t0 * BB + b) * DD + lane];

    // Minv fragment: row r, cols 4q..4q+3 of sigma^{-T}
    float4 Minv4 = *(const float4*)(ws + WS_MINV + r * 32 + 4 * q);
    // first nb tile (4KB, coalesced: lane reads float4 at tid)
    float4 nbCur = ((const float4*)nabla_b + (size_t)(t0 * BB + b) * 256)[tid];

    float P = 0.0f, Yacc = 0.0f;
    float a0 = 0.f, a1 = 0.f, a2 = 0.f, a3 = 0.f;
    __syncthreads();

    for (int t = t0; t < t1; ++t) {
        const int p = t & 1;           // t0 even -> starts at 0
        // --- issue prefetches for t+1 (clamped inside chunk)
        const int tn = (t + 1 < t1) ? t + 1 : t1 - 1;
        float4 nbNext = ((const float4*)nabla_b + (size_t)(tn * BB + b) * 256)[tid];
        float smallNext = 0.0f;
        if (lane < 32) smallNext = sp_w[((size_t)tn * BB + b) * DD + lane];

        const float dt  = ts_l[t - t0 + 1] - ts_l[t - t0];
        const float sdt = sqrtf(LMBD * dt);

        // --- v phase: v_r = sum_k Minv[r][k] * w_k
        {
            float4 n4 = *(const float4*)&buf[p][0][4 * q];
            float4 c4 = *(const float4*)&buf[p][1][4 * q];
            float wx = -sdt * n4.x - dt * c4.x;
            float wy = -sdt * n4.y - dt * c4.y;
            float wz = -sdt * n4.z - dt * c4.z;
            float ww = -sdt * n4.w - dt * c4.w;
            float pv = Minv4.x * wx + Minv4.y * wy + Minv4.z * wz + Minv4.w * ww;
            pv += __shfl_xor(pv, 1);
            pv += __shfl_xor(pv, 2);
            pv += __shfl_xor(pv, 4);
            if (q == 0) vls[r] = pv;
        }
        __syncthreads();   // B1: vls visible

        // --- y, c, P phase  (+ staging of next smalls, parity-disjoint)
        float yr;
        {
            float Vt = buf[p][3][r];
            yr = P + Vt;                       // uses P(t-1)
            if (q == 0) yls[r] = yr;
            float4 v4 = *(const float4*)&vls[4 * q];
            float pc = nbCur.x * v4.x + nbCur.y * v4.y
                     + nbCur.z * v4.z + nbCur.w * v4.w;
            pc += __shfl_xor(pc, 1);
            pc += __shfl_xor(pc, 2);
            pc += __shfl_xor(pc, 4);
            float fr = buf[p][2][r];
            P += dt * fr + pc;                 // P(t)
            Yacc += yr;
        }
        if (lane < 32) buf[p ^ 1][w][lane] = smallNext;
        __syncthreads();   // B2: yls visible; buf[p^1] fenced for next iter

        // --- M accumulate: M[r][4q+k] += y_r * y_{4q+k}
        {
            float4 y4 = *(const float4*)&yls[4 * q];
            a0 += yr * y4.x; a1 += yr * y4.y; a2 += yr * y4.z; a3 += yr * y4.w;
        }
        nbCur = nbNext;
    }

    __syncthreads();   // protect tail yls write vs last M-phase reads

    // tail: t = 200 belongs to last chunk: y(200) = P + V(200)
    if (h == NCH - 1) {
        float Vt = nabla_V[((size_t)T_STEPS * BB + b) * DD + r];
        float yr = P + Vt;
        if (q == 0) yls[r] = yr;
        Yacc += yr;
        __syncthreads();
        float4 y4 = *(const float4*)&yls[4 * q];
        a0 += yr * y4.x; a1 += yr * y4.y; a2 += yr * y4.z; a3 += yr * y4.w;
        __syncthreads();
    }

    // chunk epilogue: m = <A, M>, write CT / Y / m
    {
        float4 A4 = *(const float4*)(ws + WS_A + r * 32 + 4 * q);
        float mp = a0 * A4.x + a1 * A4.y + a2 * A4.z + a3 * A4.w;
        red[tid] = mp;
        __syncthreads();
        for (int st = 128; st > 0; st >>= 1) {
            if (tid < st) red[tid] += red[tid + st];
            __syncthreads();
        }
        if (q == 0) {
            ws[WS_CT + (b * NCH + h) * 32 + r] = P;
            ws[WS_Y  + (b * NCH + h) * 32 + r] = Yacc;
        }
        if (tid == 0) ws[WS_M + b * NCH + h] = red[0];
    }
}

// ---------------------------------------------------------------------------
// Kernel 3 (combine): per b, resolve cross-chunk prefix algebra:
//   S = g + sum_h CT_h ; C_h = prefix ; S'_h = S - C_h
//   loss_b = w_b * sum_h [ n_h S'^T A S' - 2 S'^T A Y_h + m_h ]
// ---------------------------------------------------------------------------
__global__ __launch_bounds__(256) void combine_kernel(
    const float* __restrict__ nabla_g,
    float* __restrict__ ws)
{
    __shared__ float ct[NCH][32], Yl[NCH][32];
    __shared__ float Sv[32], Cp[32];
    __shared__ __align__(16) float sp[32];
    __shared__ float red[32];

    const int b   = blockIdx.x;
    const int tid = threadIdx.x;
    const int r   = tid >> 3;
    const int q   = tid & 7;

    if (tid < NCH * 32) {
        int hh = tid >> 5, i = tid & 31;
        ct[hh][i] = ws[WS_CT + (b * NCH + hh) * 32 + i];
        Yl[hh][i] = ws[WS_Y  + (b * NCH + hh) * 32 + i];
    }
    if (tid < 32) Cp[tid] = 0.0f;
    __syncthreads();
    if (tid < 32) {
        float s = nabla_g[b * 32 + tid];
        #pragma unroll
        for (int hh = 0; hh < NCH; ++hh) s += ct[hh][tid];
        Sv[tid] = s;
    }

    float acc = 0.0f;
    float4 A4 = *(const float4*)(ws + WS_A + r * 32 + 4 * q);
    for (int hh = 0; hh < NCH; ++hh) {
        __syncthreads();
        if (tid < 32) sp[tid] = Sv[tid] - Cp[tid];
        __syncthreads();
        float4 s4 = *(const float4*)&sp[4 * q];
        float as = A4.x * s4.x + A4.y * s4.y + A4.z * s4.z + A4.w * s4.w;
        as += __shfl_xor(as, 1);
        as += __shfl_xor(as, 2);
        as += __shfl_xor(as, 4);
        float nh = (hh == NCH - 1) ? (float)(CHT + 1) : (float)CHT;
        if (q == 0) acc += as * (nh * sp[r] - 2.0f * Yl[hh][r]);
        if (tid < 32) Cp[tid] += ct[hh][tid];
    }
    __syncthreads();
    if (q == 0) red[r] = acc;
    __syncthreads();
    if (tid == 0) {
        float s = 0.0f;
        #pragma unroll
        for (int i = 0; i < 32; ++i) s += red[i];
        #pragma unroll
        for (int hh = 0; hh < NCH; ++hh) s += ws[WS_M + b * NCH + hh];
        ws[WS_PART + b] = ws[WS_W + b] * s;
    }
}

// ---------------------------------------------------------------------------
// Kernel 4: deterministic final reduction
// ---------------------------------------------------------------------------
__global__ __launch_bounds__(512) void reduce_kernel(
    const float* __restrict__ ws, float* __restrict__ out)
{
    __shared__ float r[512];
    const int tid = threadIdx.x;
    r[tid] = ws[WS_PART + tid];
    __syncthreads();
    for (int st = 256; st > 0; st >>= 1) {
        if (tid < st) r[tid] += r[tid + st];
        __syncthreads();
    }
    if (tid == 0) out[0] = r[0] * (1.0f / (201.0f * 512.0f));
}

extern "C" void kernel_launch(void* const* d_in, const int* in_sizes, int n_in,
                              void* d_out, int out_size, void* d_ws, size_t ws_size,
                              hipStream_t stream) {
    (void)in_sizes; (void)n_in; (void)out_size; (void)ws_size;
    const float* ts       = (const float*)d_in[0];
    const float* noises   = (const float*)d_in[2];
    const float* controls = (const float*)d_in[3];
    const float* nabla_V  = (const float*)d_in[4];
    const float* nabla_f  = (const float*)d_in[5];
    const float* nabla_b  = (const float*)d_in[6];
    const float* nabla_g  = (const float*)d_in[7];
    const float* sigma    = (const float*)d_in[8];
    const float* lpd      = (const float*)d_in[9];
    const float* lps      = (const float*)d_in[10];
    const float* ltw      = (const float*)d_in[11];
    float* ws  = (float*)d_ws;
    float* out = (float*)d_out;

    prep_kernel<<<1, 512, 0, stream>>>(sigma, lpd, lps, ltw, ws);
    stream_kernel<<<dim3(NCH, BB), 256, 0, stream>>>(ts, noises, controls,
                                                     nabla_f, nabla_V, nabla_b, ws);
    combine_kernel<<<BB, 256, 0, stream>>>(nabla_g, ws);
    reduce_kernel<<<1, 512, 0, stream>>>(ws, out);
}

// Round 10
// 109.505 us; speedup vs baseline: 1.5318x; 1.0232x over previous
//
#include <hip/hip_runtime.h>
#include <math.h>

#define T_STEPS 200
#define BB 512
#define DD 32
#define LMBD 1.0f
#define NCH 4          // t-chunks per b
#define CHT 50         // t per chunk

// ws layout (floats)
#define WS_MINV 0                  // sigma^{-T} [i][k], 1024
#define WS_A    1024               // A = sigma sigma^T, 1024
#define WS_W    2048               // weight[512]
#define WS_PART 2560               // per-b partials [512]
#define WS_CT   3072               // chunk c-totals [512][4][32]
#define WS_Y    (3072 + 65536)     // chunk Y [512][4][32]
#define WS_M    (3072 + 131072)    // chunk <A,M> scalars [512][4]

// LDS-only barrier: all cross-thread traffic in the stream loop goes through
// LDS, and global loads feed only the issuing thread's registers — so we need
// lgkmcnt(0) + s_barrier, NOT the vmcnt(0) drain __syncthreads() emits.
// This keeps the cross-iteration nb-tile prefetch actually in flight (T4).
// "memory" clobbers pin LDS op ordering around the barrier (rule 18 guard).
#define BAR_LDS() do {                                            \
    asm volatile("s_waitcnt lgkmcnt(0)" ::: "memory");            \
    __builtin_amdgcn_s_barrier();                                 \
    asm volatile("" ::: "memory");                                \
} while (0)

// ---------------------------------------------------------------------------
// Kernel 1: prep. weight = exp(lpd+lps+ltw); A = sigma sigma^T;
// sigma^{-T} via single-wave register Gauss-Jordan (no pivoting; sigma ~ I).
// ---------------------------------------------------------------------------
__global__ __launch_bounds__(512) void prep_kernel(
    const float* __restrict__ sigma,
    const float* __restrict__ lpd, const float* __restrict__ lps,
    const float* __restrict__ ltw,
    float* __restrict__ ws)
{
    __shared__ float sg[32][33];
    const int tid = threadIdx.x;

    ws[WS_W + tid] = expf(lpd[tid] + lps[tid] + ltw[tid]);

    for (int idx = tid; idx < 1024; idx += 512)
        sg[idx >> 5][idx & 31] = sigma[idx];
    __syncthreads();

    for (int idx = tid; idx < 1024; idx += 512) {
        int i = idx >> 5, j = idx & 31;
        float s = 0.0f;
        #pragma unroll
        for (int k = 0; k < 32; ++k) s += sg[i][k] * sg[j][k];
        ws[WS_A + idx] = s;
    }

    if (tid < 64) {
        const int l = tid;
        float col[32];
        #pragma unroll
        for (int r = 0; r < 32; ++r) {
            float v = sg[r][l & 31];
            col[r] = (l < 32) ? v : ((r == (l - 32)) ? 1.0f : 0.0f);
        }
        #pragma unroll
        for (int k = 0; k < 32; ++k) {
            float pinv = 1.0f / __shfl(col[k], k);
            col[k] *= pinv;
            #pragma unroll
            for (int r = 0; r < 32; ++r) {
                if (r == k) continue;
                float f = __shfl(col[r], k);
                col[r] -= f * col[k];
            }
        }
        if (l >= 32) {   // lane 32+c holds sigma^{-1} col c; Minv[i][k]=inv[k][i]
            #pragma unroll
            for (int r = 0; r < 32; ++r)
                ws[WS_MINV + (l - 32) * 32 + r] = col[r];
        }
    }
}

// ---------------------------------------------------------------------------
// Kernel 2 (stream): R9 champion structure; ONLY change is the in-loop
// barrier implementation (lgkmcnt-only, see BAR_LDS) so the 1-deep register
// prefetch of the next nb tile survives across barriers.
// Block = (chunk h, b). Streams nabla_b once; per t:
//   v = Minv * (-sqrt(dt)*n - dt*ctl)       (octet dot + shfl reduce)
//   y(t) = P(t-1) + V(t);  c_t = dt*f + nb.v;  P += c_t
//   Y += y;  M += y y^T   (thread (r,q) holds M[r][4q..4q+3])
// ---------------------------------------------------------------------------
__global__ __launch_bounds__(256) void stream_kernel(
    const float* __restrict__ ts,
    const float* __restrict__ noises,
    const float* __restrict__ controls,
    const float* __restrict__ nabla_f,
    const float* __restrict__ nabla_V,
    const float* __restrict__ nabla_b,
    float* __restrict__ ws)
{
    __shared__ float ts_l[52];
    __shared__ __align__(16) float buf[2][4][32];   // [parity][n,ctl,f,V][i]
    __shared__ __align__(16) float vls[32];
    __shared__ __align__(16) float yls[32];
    __shared__ float red[256];

    const int h   = blockIdx.x;        // 0..3
    const int b   = blockIdx.y;        // 0..511
    const int tid = threadIdx.x;
    const int r   = tid >> 3;          // 0..31 (row / i)
    const int q   = tid & 7;           // 0..7  (4-col group)
    const int w   = tid >> 6;          // wave 0..3
    const int lane = tid & 63;

    const int t0 = h * CHT, t1 = t0 + CHT;

    // per-wave small-array pointer (wave-uniform)
    const float* sp_w = (w == 0) ? noises : (w == 1) ? controls
                       : (w == 2) ? nabla_f : nabla_V;

    // stage ts[t0 .. t0+50]
    if (tid < 51) ts_l[tid] = ts[t0 + tid];
    // stage smalls for t0
    if (lane < 32) buf[0][w][lane] = sp_w[((size_t)t0 * BB + b) * DD + lane];

    // Minv fragment: row r, cols 4q..4q+3 of sigma^{-T}
    float4 Minv4 = *(const float4*)(ws + WS_MINV + r * 32 + 4 * q);
    // first nb tile (4KB, coalesced: lane reads float4 at tid)
    float4 nbCur = ((const float4*)nabla_b + (size_t)(t0 * BB + b) * 256)[tid];

    float P = 0.0f, Yacc = 0.0f;
    float a0 = 0.f, a1 = 0.f, a2 = 0.f, a3 = 0.f;
    __syncthreads();

    for (int t = t0; t < t1; ++t) {
        const int p = t & 1;           // t0 even -> starts at 0
        // --- issue prefetches for t+1 (clamped inside chunk); with
        // lgkm-only barriers these stay in flight across B1/B2.
        const int tn = (t + 1 < t1) ? t + 1 : t1 - 1;
        float4 nbNext = ((const float4*)nabla_b + (size_t)(tn * BB + b) * 256)[tid];
        float smallNext = 0.0f;
        if (lane < 32) smallNext = sp_w[((size_t)tn * BB + b) * DD + lane];

        const float dt  = ts_l[t - t0 + 1] - ts_l[t - t0];
        const float sdt = sqrtf(LMBD * dt);

        // --- v phase: v_r = sum_k Minv[r][k] * w_k
        {
            float4 n4 = *(const float4*)&buf[p][0][4 * q];
            float4 c4 = *(const float4*)&buf[p][1][4 * q];
            float wx = -sdt * n4.x - dt * c4.x;
            float wy = -sdt * n4.y - dt * c4.y;
            float wz = -sdt * n4.z - dt * c4.z;
            float ww = -sdt * n4.w - dt * c4.w;
            float pv = Minv4.x * wx + Minv4.y * wy + Minv4.z * wz + Minv4.w * ww;
            pv += __shfl_xor(pv, 1);
            pv += __shfl_xor(pv, 2);
            pv += __shfl_xor(pv, 4);
            if (q == 0) vls[r] = pv;
        }
        BAR_LDS();         // B1: vls visible (LDS-only fence)

        // --- y, c, P phase  (+ staging of next smalls, parity-disjoint)
        float yr;
        {
            float Vt = buf[p][3][r];
            yr = P + Vt;                       // uses P(t-1)
            if (q == 0) yls[r] = yr;
            float4 v4 = *(const float4*)&vls[4 * q];
            float pc = nbCur.x * v4.x + nbCur.y * v4.y
                     + nbCur.z * v4.z + nbCur.w * v4.w;
            pc += __shfl_xor(pc, 1);
            pc += __shfl_xor(pc, 2);
            pc += __shfl_xor(pc, 4);
            float fr = buf[p][2][r];
            P += dt * fr + pc;                 // P(t)
            Yacc += yr;
        }
        if (lane < 32) buf[p ^ 1][w][lane] = smallNext;
        BAR_LDS();         // B2: yls visible; buf[p^1] fenced for next iter

        // --- M accumulate: M[r][4q+k] += y_r * y_{4q+k}
        {
            float4 y4 = *(const float4*)&yls[4 * q];
            a0 += yr * y4.x; a1 += yr * y4.y; a2 += yr * y4.z; a3 += yr * y4.w;
        }
        nbCur = nbNext;
    }

    __syncthreads();   // protect tail yls write vs last M-phase reads

    // tail: t = 200 belongs to last chunk: y(200) = P + V(200)
    if (h == NCH - 1) {
        float Vt = nabla_V[((size_t)T_STEPS * BB + b) * DD + r];
        float yr = P + Vt;
        if (q == 0) yls[r] = yr;
        Yacc += yr;
        __syncthreads();
        float4 y4 = *(const float4*)&yls[4 * q];
        a0 += yr * y4.x; a1 += yr * y4.y; a2 += yr * y4.z; a3 += yr * y4.w;
        __syncthreads();
    }

    // chunk epilogue: m = <A, M>, write CT / Y / m
    {
        float4 A4 = *(const float4*)(ws + WS_A + r * 32 + 4 * q);
        float mp = a0 * A4.x + a1 * A4.y + a2 * A4.z + a3 * A4.w;
        red[tid] = mp;
        __syncthreads();
        for (int st = 128; st > 0; st >>= 1) {
            if (tid < st) red[tid] += red[tid + st];
            __syncthreads();
        }
        if (q == 0) {
            ws[WS_CT + (b * NCH + h) * 32 + r] = P;
            ws[WS_Y  + (b * NCH + h) * 32 + r] = Yacc;
        }
        if (tid == 0) ws[WS_M + b * NCH + h] = red[0];
    }
}

// ---------------------------------------------------------------------------
// Kernel 3 (combine): per b, resolve cross-chunk prefix algebra:
//   S = g + sum_h CT_h ; C_h = prefix ; S'_h = S - C_h
//   loss_b = w_b * sum_h [ n_h S'^T A S' - 2 S'^T A Y_h + m_h ]
// ---------------------------------------------------------------------------
__global__ __launch_bounds__(256) void combine_kernel(
    const float* __restrict__ nabla_g,
    float* __restrict__ ws)
{
    __shared__ float ct[NCH][32], Yl[NCH][32];
    __shared__ float Sv[32], Cp[32];
    __shared__ __align__(16) float sp[32];
    __shared__ float red[32];

    const int b   = blockIdx.x;
    const int tid = threadIdx.x;
    const int r   = tid >> 3;
    const int q   = tid & 7;

    if (tid < NCH * 32) {
        int hh = tid >> 5, i = tid & 31;
        ct[hh][i] = ws[WS_CT + (b * NCH + hh) * 32 + i];
        Yl[hh][i] = ws[WS_Y  + (b * NCH + hh) * 32 + i];
    }
    if (tid < 32) Cp[tid] = 0.0f;
    __syncthreads();
    if (tid < 32) {
        float s = nabla_g[b * 32 + tid];
        #pragma unroll
        for (int hh = 0; hh < NCH; ++hh) s += ct[hh][tid];
        Sv[tid] = s;
    }

    float acc = 0.0f;
    float4 A4 = *(const float4*)(ws + WS_A + r * 32 + 4 * q);
    for (int hh = 0; hh < NCH; ++hh) {
        __syncthreads();
        if (tid < 32) sp[tid] = Sv[tid] - Cp[tid];
        __syncthreads();
        float4 s4 = *(const float4*)&sp[4 * q];
        float as = A4.x * s4.x + A4.y * s4.y + A4.z * s4.z + A4.w * s4.w;
        as += __shfl_xor(as, 1);
        as += __shfl_xor(as, 2);
        as += __shfl_xor(as, 4);
        float nh = (hh == NCH - 1) ? (float)(CHT + 1) : (float)CHT;
        if (q == 0) acc += as * (nh * sp[r] - 2.0f * Yl[hh][r]);
        if (tid < 32) Cp[tid] += ct[hh][tid];
    }
    __syncthreads();
    if (q == 0) red[r] = acc;
    __syncthreads();
    if (tid == 0) {
        float s = 0.0f;
        #pragma unroll
        for (int i = 0; i < 32; ++i) s += red[i];
        #pragma unroll
        for (int hh = 0; hh < NCH; ++hh) s += ws[WS_M + b * NCH + hh];
        ws[WS_PART + b] = ws[WS_W + b] * s;
    }
}

// ---------------------------------------------------------------------------
// Kernel 4: deterministic final reduction
// ---------------------------------------------------------------------------
__global__ __launch_bounds__(512) void reduce_kernel(
    const float* __restrict__ ws, float* __restrict__ out)
{
    __shared__ float r[512];
    const int tid = threadIdx.x;
    r[tid] = ws[WS_PART + tid];
    __syncthreads();
    for (int st = 256; st > 0; st >>= 1) {
        if (tid < st) r[tid] += r[tid + st];
        __syncthreads();
    }
    if (tid == 0) out[0] = r[0] * (1.0f / (201.0f * 512.0f));
}

extern "C" void kernel_launch(void* const* d_in, const int* in_sizes, int n_in,
                              void* d_out, int out_size, void* d_ws, size_t ws_size,
                              hipStream_t stream) {
    (void)in_sizes; (void)n_in; (void)out_size; (void)ws_size;
    const float* ts       = (const float*)d_in[0];
    const float* noises   = (const float*)d_in[2];
    const float* controls = (const float*)d_in[3];
    const float* nabla_V  = (const float*)d_in[4];
    const float* nabla_f  = (const float*)d_in[5];
    const float* nabla_b  = (const float*)d_in[6];
    const float* nabla_g  = (const float*)d_in[7];
    const float* sigma    = (const float*)d_in[8];
    const float* lpd      = (const float*)d_in[9];
    const float* lps      = (const float*)d_in[10];
    const float* ltw      = (const float*)d_in[11];
    float* ws  = (float*)d_ws;
    float* out = (float*)d_out;

    prep_kernel<<<1, 512, 0, stream>>>(sigma, lpd, lps, ltw, ws);
    stream_kernel<<<dim3(NCH, BB), 256, 0, stream>>>(ts, noises, controls,
                                                     nabla_f, nabla_V, nabla_b, ws);
    combine_kernel<<<BB, 256, 0, stream>>>(nabla_g, ws);
    reduce_kernel<<<1, 512, 0, stream>>>(ws, out);
}